// Round 11
// baseline (201.870 us; speedup 1.0000x reference)
//
#include <hip/hip_runtime.h>
#include <stdint.h>

// out[p,b,o] = sum_i x*w0 + (1-x)*w1 = sum_i x*(w0-w1) + sum_i w1
// R19: R16 hot loop verbatim (1024B w strips, MFMA, verified fragments,
// 162.6us) + GUARANTEED same-XCD pair formation. Re-audit showed R16 is
// HBM-saturated at ~1.09 GiB -- i.e. the (t,t+128) same-XCD pairing guess
// FAILED and w is fetched twice. Fix: read HW_REG_XCC_ID (m09-verified) +
// per-XCD atomic arrival ticket -> (tile, half) = (xcd*16 + rk/2, rk&1).
// Same-L2 pairs by construction, adjacent arrival (minimal drift), mapping-
// agnostic. Coverage exact: 52KB LDS -> 1 block/CU -> all 256 co-resident
// -> 32 ranks/XCD. Light pacing every 4 steps (budget 32 x s_sleep(1));
// true pairs exit the spin fast (R18's cross-XCD pairs never could).

#define NP 16
#define NB 512
#define NI 2048
#define NO 2048
#define JW 64               // u32 words per i-row in xp
#define OT 256              // o-columns per block
#define KS 32               // k-rows per step
#define NST (NI / KS)       // 64 steps
#define XP_WORDS (NP * NB * JW)   // 524288 u32 = 2 MiB

typedef __attribute__((ext_vector_type(8))) short short8;
typedef __attribute__((ext_vector_type(4))) float f32x4;

__global__ __launch_bounds__(256) void pack_x_kernel(const float* __restrict__ x,
                                                     uint32_t* __restrict__ xp) {
    const int gtid = blockIdx.x * 256 + threadIdx.x;
    const int row  = gtid >> 6;     // p*NB + b
    const int lane = gtid & 63;
    const float* src = x + (size_t)row * NI;
    unsigned long long* dst = (unsigned long long*)(xp + (size_t)row * JW);
#pragma unroll 4
    for (int k = 0; k < NI / 64; ++k) {
        const float v = src[k * 64 + lane];
        const unsigned long long m = __ballot(v != 0.0f);
        if (lane == 0) dst[k] = m;
    }
}

// bf16 truncation (exact for d in {-1,0,1} and w1 in {0,1})
#define BF16(f) ((uint32_t)(__float_as_uint(f) >> 16))

// issue next step's w: k-rows 4wv..4wv+3, lane cols 4l..4l+3, both mats
#define WISS(s0_, s1_) do {                                                    \
    _Pragma("unroll")                                                          \
    for (int _j = 0; _j < 4; ++_j) {                                           \
        s0_[_j] = *(const f32x4*)(w0n + (size_t)_j * NO);                      \
        s1_[_j] = *(const f32x4*)(w1n + (size_t)_j * NO);                      \
    }                                                                          \
    w0n += (size_t)KS * NO; w1n += (size_t)KS * NO;                            \
} while (0)

// convert a w set -> bf16 d tile rows 4wv..+3 of bds[b_]; colsum(w1).
#define CVT(s0_, s1_, b_) do {                                                 \
    _Pragma("unroll")                                                          \
    for (int _c = 0; _c < 4; ++_c) {                                           \
        const float _d0 = s0_[0][_c] - s1_[0][_c];                             \
        const float _d1 = s0_[1][_c] - s1_[1][_c];                             \
        const float _d2 = s0_[2][_c] - s1_[2][_c];                             \
        const float _d3 = s0_[3][_c] - s1_[3][_c];                             \
        cs[_c] += s1_[0][_c] + s1_[1][_c] + s1_[2][_c] + s1_[3][_c];           \
        uint2 _st;                                                             \
        _st.x = BF16(_d0) | (BF16(_d1) << 16);                                 \
        _st.y = BF16(_d2) | (BF16(_d3) << 16);                                 \
        *(uint2*)&bds[b_][4 * lane + _c][4 * wv] = _st;                        \
    }                                                                          \
} while (0)

// issue next x words (2 m-frag rows' step-word) and bump
#define XISS(xw) do {                                                          \
    xw[0] = xn[0]; xw[1] = xn[1024];                                           \
    xn += 1;                                                                   \
} while (0)

// expand A-frags from packed-x words: bit -> bf16 {0,1}  (R14-verified)
#define AEXP(afr, xw) do {                                                     \
    _Pragma("unroll")                                                          \
    for (int _mi = 0; _mi < 2; ++_mi) {                                        \
        const uint32_t _by = (xw[_mi] >> klo8) & 0xFFu;                        \
        union { uint32_t u[4]; short8 s; } _cv;                                \
        _cv.u[0] = (_by & 1u   ? 0x3F80u : 0u) | (_by & 2u   ? 0x3F800000u : 0u); \
        _cv.u[1] = (_by & 4u   ? 0x3F80u : 0u) | (_by & 8u   ? 0x3F800000u : 0u); \
        _cv.u[2] = (_by & 16u  ? 0x3F80u : 0u) | (_by & 32u  ? 0x3F800000u : 0u); \
        _cv.u[3] = (_by & 64u  ? 0x3F80u : 0u) | (_by & 128u ? 0x3F800000u : 0u); \
        afr[_mi] = _cv.s;                                                      \
    }                                                                          \
} while (0)

// read B-frags from bds[b_] (two b64s each; pitch 88B -> ~2-way, free) + MFMA
#define BRDMFMA(afr, b_) do {                                                  \
    _Pragma("unroll")                                                          \
    for (int _nj = 0; _nj < 16; ++_nj) {                                       \
        union { uint2 q[2]; short8 s; } _u;                                    \
        _u.q[0] = *(const uint2*)&bds[b_][_nj * 16 + lanelo][klo8];            \
        _u.q[1] = *(const uint2*)&bds[b_][_nj * 16 + lanelo][klo8 + 4];        \
        _Pragma("unroll")                                                      \
        for (int _mi = 0; _mi < 2; ++_mi)                                      \
            acc[_mi][_nj] = __builtin_amdgcn_mfma_f32_16x16x32_bf16(           \
                afr[_mi], _u.s, acc[_mi][_nj], 0, 0, 0);                       \
    }                                                                          \
} while (0)

// lgkmcnt-only barrier: LDS visibility without draining the w vmcnt FIFO
#define BARLDS() asm volatile("s_waitcnt lgkmcnt(0)\n\ts_barrier" ::: "memory")

// pair lockstep: thread 0 arrives at phase ph_ and bounded-spins for partner.
// Pure perf hint: timeout -> proceed. Partner is same-XCD & arrival-adjacent
// -> expected exit in <100 cyc; cap ~0.85us/phase.
#define PACE(ph_) do {                                                         \
    if (tid == 0) {                                                            \
        const uint32_t _tgt = 2u * (uint32_t)(ph_);                            \
        __hip_atomic_fetch_add(&pace[t], 1u, __ATOMIC_RELAXED,                 \
                               __HIP_MEMORY_SCOPE_AGENT);                      \
        int _budget = 32;                                                      \
        while (__hip_atomic_load(&pace[t], __ATOMIC_RELAXED,                   \
                                 __HIP_MEMORY_SCOPE_AGENT) < _tgt              \
               && --_budget > 0)                                               \
            __builtin_amdgcn_s_sleep(1);                                       \
    }                                                                          \
} while (0)

__global__ __launch_bounds__(512, 2) void evo_w4(const float* __restrict__ w,
                                                 const uint32_t* __restrict__ xp,
                                                 uint32_t* __restrict__ tick,
                                                 uint32_t* __restrict__ pace,
                                                 float* __restrict__ out) {
    __shared__ __align__(16) uint16_t bds[2][OT][44];  // 44 KB, dbuf d tile
    __shared__ float csl[8][64][4];                    // 8 KB, colsum partials
    __shared__ uint32_t meta;                          // tile/half broadcast

    const int tid    = threadIdx.x;
    const int lane   = tid & 63;
    const int wv     = __builtin_amdgcn_readfirstlane(tid >> 6);  // 0..7
    const int lanelo = lane & 15;
    const int klo8   = (lane >> 4) * 8;

    // ---- same-XCD pair formation: XCC_ID + per-XCD arrival ticket ----
    if (tid == 0) {
        uint32_t xcd;
        asm volatile("s_getreg_b32 %0, hwreg(HW_REG_XCC_ID)" : "=s"(xcd));
        xcd &= 7u;
        const uint32_t rk = __hip_atomic_fetch_add(&tick[xcd], 1u,
                                __ATOMIC_RELAXED, __HIP_MEMORY_SCOPE_AGENT) & 31u;
        meta = xcd * 32u + rk;
    }
    __syncthreads();
    const uint32_t gr = meta;
    const int t  = (int)(gr >> 1) & 127;  // tile 0..127 (same-XCD pair shares t)
    const int h  = (int)(gr & 1u);        // b-half 0..1
    const int p  = t >> 3;                // 0..15
    const int og = t & 7;                 // 0..7

    const size_t wq = (size_t)NI * NO;
    const float* w0n = w + (size_t)p * wq + (size_t)(4 * wv) * NO
                     + og * OT + 4 * lane;
    const float* w1n = w0n + (size_t)NP * wq;
    const uint32_t* xn = xp + ((size_t)p * NB + h * 256 + wv * 32 + lanelo) * JW;

    f32x4 acc[2][16];
#pragma unroll
    for (int mi = 0; mi < 2; ++mi)
#pragma unroll
        for (int nj = 0; nj < 16; ++nj) acc[mi][nj] = (f32x4)0.0f;
    float cs[4] = {0.0f, 0.0f, 0.0f, 0.0f};

    f32x4 wA0[4], wA1[4], wB0[4], wB1[4];
    uint32_t xwA[2], xwB[2];

    // ---- prologue: w(0),w(1),x(0),x(1) in flight; cvt w(0)->buf0; w(2) ----
    WISS(wA0, wA1);               // w(0)
    WISS(wB0, wB1);               // w(1)
    XISS(xwA); XISS(xwB);         // x(0), x(1)
    CVT(wA0, wA1, 0);             // waits w(0) only
    WISS(wA0, wA1);               // w(2)
    BARLDS();

    // ---- 64 steps, 2/iter; w issue->cvt distance = 2 full steps ----
#pragma unroll 1
    for (int ss = 0; ss < 32; ++ss) {
        if ((ss & 1) == 0) PACE((ss >> 1) + 1);   // every 4 steps
        {   // even step s = 2ss : buf0, xwA
            short8 afr[2];
            AEXP(afr, xwA);
            if (ss < 31) XISS(xwA);            // x(2ss+2)
            BRDMFMA(afr, 0);
            CVT(wB0, wB1, 1);                  // w(2ss+1) -> buf1
            if (ss < 31) WISS(wB0, wB1);       // w(2ss+3)
            BARLDS();
        }
        {   // odd step s = 2ss+1 : buf1, xwB
            short8 afr[2];
            AEXP(afr, xwB);
            if (ss < 31) XISS(xwB);            // x(2ss+3)
            BRDMFMA(afr, 1);
            if (ss < 31) {
                CVT(wA0, wA1, 0);              // w(2ss+2) -> buf0
                if (ss < 30) WISS(wA0, wA1);   // w(2ss+4), last valid = w62
                BARLDS();
            }
        }
    }

    // ---- colsum reduce + epilogue (exact: integers <= 2048) ----
    csl[wv][lane][0] = cs[0]; csl[wv][lane][1] = cs[1];
    csl[wv][lane][2] = cs[2]; csl[wv][lane][3] = cs[3];
    __syncthreads();

    float* obase = out + ((size_t)p * NB + h * 256 + wv * 32) * NO + og * OT;
#pragma unroll
    for (int nj = 0; nj < 16; ++nj) {
        const int colT = nj * 16 + lanelo;
        float csT = 0.0f;
#pragma unroll
        for (int q = 0; q < 8; ++q) csT += csl[q][colT >> 2][colT & 3];
#pragma unroll
        for (int mi = 0; mi < 2; ++mi) {
            const int r0 = mi * 16 + (lane >> 4) * 4;
            const f32x4 v = acc[mi][nj];
            obase[(size_t)(r0 + 0) * NO + colT] = v[0] + csT;
            obase[(size_t)(r0 + 1) * NO + colT] = v[1] + csT;
            obase[(size_t)(r0 + 2) * NO + colT] = v[2] + csT;
            obase[(size_t)(r0 + 3) * NO + colT] = v[3] + csT;
        }
    }
}

extern "C" void kernel_launch(void* const* d_in, const int* in_sizes, int n_in,
                              void* d_out, int out_size, void* d_ws, size_t ws_size,
                              hipStream_t stream) {
    const float* x = (const float*)d_in[0];   // (16,512,2048) fp32 {0,1}
    const float* w = (const float*)d_in[1];   // (2,16,1,2048,2048) fp32 {0,1}
    float* out     = (float*)d_out;           // (16,512,2048) fp32
    uint32_t* xp   = (uint32_t*)d_ws;         // 2 MiB packed x
    uint32_t* tick = xp + XP_WORDS;           // 8 per-XCD tickets
    uint32_t* pace = tick + 8;                // 128 pair counters

    hipMemsetAsync(tick, 0, (8 + 128) * sizeof(uint32_t), stream);
    pack_x_kernel<<<dim3((NP * NB * 64) / 256), dim3(256), 0, stream>>>(x, xp);
    evo_w4<<<dim3(256), dim3(512), 0, stream>>>(w, xp, tick, pace, out);
}